// Round 1
// baseline (8701.591 us; speedup 1.0000x reference)
//
#include <hip/hip_runtime.h>
#include <hip/hip_bf16.h>
#include <math.h>

#define N_NODES 19
#define D_IN    100
#define HID     128
#define T_SEQ   250
#define BATCH   64
#define NC      4
#define KTOT    228          // D_IN + HID
#define G4      512          // 4*HID
#define FEAT    2432         // N_NODES*HID

// workspace layout (float offsets)
#define SZ_WT    (N_NODES*KTOT*G4)   // packed [n][k][512] fused weights
#define OFF_WT   0
#define OFF_BIAS (OFF_WT + SZ_WT)
#define SZ_BIAS  (N_NODES*G4)
#define OFF_W1T  (OFF_BIAS + SZ_BIAS)
#define SZ_W1T   (FEAT*HID)          // W1 transposed [k][128]
#define OFF_HF   (OFF_W1T + SZ_W1T)
#define SZ_HF    (BATCH*N_NODES*HID)
#define PACK_TOTAL (SZ_WT + SZ_BIAS + SZ_W1T)

#define CH 8                 // batch chunks
#define BW (BATCH/CH)        // 8 batch rows per workgroup
#define XH_STRIDE 232

__device__ __forceinline__ float sigmoid_f(float x) {
    return 1.0f / (1.0f + expf(-x));
}

// Pack fused weights k-major, combined bias, transposed W1.
__global__ __launch_bounds__(256) void pack_kernel(
        const float* __restrict__ W_ih, const float* __restrict__ W_hh,
        const float* __restrict__ b_ih, const float* __restrict__ b_hh,
        const float* __restrict__ W1, float* __restrict__ ws) {
    int id = blockIdx.x * 256 + threadIdx.x;
    if (id < SZ_WT) {
        int g = id % G4;
        int k = (id / G4) % KTOT;
        int n = id / (G4 * KTOT);
        float v = (k < D_IN) ? W_ih[(n*G4 + g)*D_IN + k]
                             : W_hh[(n*G4 + g)*HID + (k - D_IN)];
        ws[OFF_WT + id] = v;
        return;
    }
    int id2 = id - SZ_WT;
    if (id2 < SZ_BIAS) {
        ws[OFF_BIAS + id2] = b_ih[id2] + b_hh[id2];
        return;
    }
    int id3 = id2 - SZ_BIAS;
    if (id3 < SZ_W1T) {
        int j = id3 % HID;          // output unit
        int k = id3 / HID;          // feature
        ws[OFF_W1T + id3] = W1[j*FEAT + k];
        return;
    }
}

// One workgroup = (node, 8 batch rows). 256 threads.
// thread t: hidden index j = t&127, batch group bg = t>>7 (4 rows each).
// Each thread owns gates i,f,g,o of hidden j for its 4 batch rows; c in regs.
__global__ __launch_bounds__(256) void lstm_kernel(
        const float* __restrict__ inp, float* __restrict__ ws) {
    __shared__ float xh[BW][XH_STRIDE];   // [b][0:100)=x_t, [100:228)=h
    const int tid = threadIdx.x;
    const int n  = blockIdx.x / CH;
    const int b0 = (blockIdx.x % CH) * BW;
    const int j  = tid & 127;
    const int bg = tid >> 7;              // 0 or 1

    const float* __restrict__ Wt   = ws + OFF_WT + (size_t)n*KTOT*G4;
    const float* __restrict__ bias = ws + OFF_BIAS + n*G4;
    const float bi = bias[j];
    const float bf = bias[j + 128];
    const float bgc = bias[j + 256];
    const float bo = bias[j + 384];

    float c[4] = {0.f, 0.f, 0.f, 0.f};

    // zero LDS (h part must start at 0)
    for (int idx = tid; idx < BW*XH_STRIDE; idx += 256)
        (&xh[0][0])[idx] = 0.f;
    __syncthreads();

    for (int t = 0; t < T_SEQ; ++t) {
        // stage x_t rows for the 8 batch rows
        for (int idx = tid; idx < BW*D_IN; idx += 256) {
            int b = idx / D_IN, d = idx - b*D_IN;
            xh[b][d] = inp[(((b0 + b)*N_NODES + n)*T_SEQ + t)*D_IN + d];
        }
        __syncthreads();

        float acc[4][4];
        #pragma unroll
        for (int q = 0; q < 4; ++q) {
            acc[q][0] = 0.f; acc[q][1] = 0.f; acc[q][2] = 0.f; acc[q][3] = 0.f;
        }

        #pragma unroll 2
        for (int k = 0; k < KTOT; ++k) {
            const float* wk = Wt + (size_t)k*G4;
            float wi = wk[j];
            float wf = wk[j + 128];
            float wg = wk[j + 256];
            float wo = wk[j + 384];
            #pragma unroll
            for (int q = 0; q < 4; ++q) {
                float v = xh[bg*4 + q][k];
                acc[q][0] = fmaf(wi, v, acc[q][0]);
                acc[q][1] = fmaf(wf, v, acc[q][1]);
                acc[q][2] = fmaf(wg, v, acc[q][2]);
                acc[q][3] = fmaf(wo, v, acc[q][3]);
            }
        }
        __syncthreads();   // all reads of xh done before h overwrite

        #pragma unroll
        for (int q = 0; q < 4; ++q) {
            float ii = sigmoid_f(acc[q][0] + bi);
            float ff = sigmoid_f(acc[q][1] + bf);
            float gg = tanhf(acc[q][2] + bgc);
            float oo = sigmoid_f(acc[q][3] + bo);
            float cn = ff*c[q] + ii*gg;
            c[q] = cn;
            xh[bg*4 + q][D_IN + j] = oo * tanhf(cn);
        }
        // next iteration's x-stage writes a disjoint LDS region; the
        // __syncthreads at top of next iteration orders h-writes vs reads
    }
    __syncthreads();

    // write final h -> hfinal[b][n][128]
    for (int idx = tid; idx < BW*HID; idx += 256) {
        int b = idx / HID, jj = idx - b*HID;
        ws[OFF_HF + (size_t)((b0 + b)*N_NODES + n)*HID + jj] = xh[b][D_IN + jj];
    }
}

// Head: one block per batch row; 128 threads, one per hidden unit.
__global__ __launch_bounds__(128) void head_kernel(
        const float* __restrict__ ws,
        const float* __restrict__ b1, const float* __restrict__ W2,
        const float* __restrict__ b2, float* __restrict__ out) {
    __shared__ float comb[FEAT];
    __shared__ float hid[HID];
    const int b = blockIdx.x, t = threadIdx.x;
    const float* hf = ws + OFF_HF + (size_t)b*FEAT;
    for (int i = t; i < FEAT; i += 128) comb[i] = hf[i];
    __syncthreads();

    const float* w1t = ws + OFF_W1T;
    float acc = 0.f;
    #pragma unroll 4
    for (int k = 0; k < FEAT; ++k)
        acc = fmaf(comb[k], w1t[(size_t)k*HID + t], acc);
    acc += b1[t];
    hid[t] = fmaxf(acc, 0.f);
    __syncthreads();

    if (t < NC) {
        float a = b2[t];
        for (int k = 0; k < HID; ++k)
            a = fmaf(hid[k], W2[t*HID + k], a);
        out[b*NC + t] = a;
    }
}

extern "C" void kernel_launch(void* const* d_in, const int* in_sizes, int n_in,
                              void* d_out, int out_size, void* d_ws, size_t ws_size,
                              hipStream_t stream) {
    const float* inp  = (const float*)d_in[0];
    // d_in[1] = seq_lengths (int64) — reference ignores it
    const float* W_ih = (const float*)d_in[2];
    const float* W_hh = (const float*)d_in[3];
    const float* b_ih = (const float*)d_in[4];
    const float* b_hh = (const float*)d_in[5];
    // d_in[6] = W1
    const float* W1   = (const float*)d_in[6];
    const float* b1   = (const float*)d_in[7];
    const float* W2   = (const float*)d_in[8];
    const float* b2   = (const float*)d_in[9];
    float* out = (float*)d_out;
    float* ws  = (float*)d_ws;

    pack_kernel<<<(PACK_TOTAL + 255)/256, 256, 0, stream>>>(W_ih, W_hh, b_ih, b_hh, W1, ws);
    lstm_kernel<<<N_NODES*CH, 256, 0, stream>>>(inp, ws);
    head_kernel<<<BATCH, 128, 0, stream>>>(ws, b1, W2, b2, out);
}

// Round 2
// 715.389 us; speedup vs baseline: 12.1634x; 12.1634x over previous
//
#include <hip/hip_runtime.h>
#include <hip/hip_bf16.h>

#define NN   19
#define DIN  100
#define HID  128
#define TT   250
#define BB   64
#define NC   4
#define FEAT 2432          // NN*HID

typedef __attribute__((ext_vector_type(8))) short s8v;
typedef __attribute__((ext_vector_type(4))) float f4v;

// ---- workspace layout ----
// [0]                : bf16 weight fragments, SZ_BF ushorts
// float offsets thereafter:
#define SZ_BF   (NN*8*4*8*512)        // 2,490,368 ushorts (n, hb, nt, kt, lane, e)
#define OFF_W1T (SZ_BF/2)             // 1,245,184 (float offset)
#define SZ_W1T  (FEAT*HID)            // 311,296
#define OFF_HF  (OFF_W1T + SZ_W1T)    // 1,556,480
#define SZ_HF   (BB*FEAT)             // 155,648
#define PACK_TOTAL (SZ_BF + SZ_W1T)   // 2,801,664 = 10944*256

__device__ __forceinline__ unsigned short f2bf(float x) {
    union { float f; unsigned u; } v; v.f = x;
    unsigned r = v.u + 0x7FFF + ((v.u >> 16) & 1);   // RNE
    return (unsigned short)(r >> 16);
}
__device__ __forceinline__ float sigf(float x) {
    return 1.f / (1.f + exp2f(-1.4426950408889634f * x));
}
__device__ __forceinline__ float tnhf(float x) {
    return 1.f - 2.f / (exp2f(2.8853900817779268f * x) + 1.f);
}

// Pack weights into per-wave MFMA B-fragments (bf16) + W1 transposed (fp32).
// B-frag element (n, hb, nt, kt, lane, e) = Wfused[k][g], k = kt*32+(lane>>4)*8+e,
// g = nt*128 + hb*16 + (lane&15);  k<100 -> W_ih, 100<=k<228 -> W_hh, else 0.
__global__ __launch_bounds__(256) void pack_kernel(
        const float* __restrict__ W_ih, const float* __restrict__ W_hh,
        const float* __restrict__ W1,
        unsigned short* __restrict__ bfw, float* __restrict__ w1t) {
    int id = blockIdx.x * 256 + threadIdx.x;
    if (id < SZ_BF) {
        int e    = id & 7;
        int lane = (id >> 3) & 63;
        int kt   = (id >> 9) & 7;
        int nt   = (id >> 12) & 3;
        int hb   = (id >> 14) & 7;
        int n    = id >> 17;
        int k = kt * 32 + (lane >> 4) * 8 + e;
        int g = nt * 128 + hb * 16 + (lane & 15);
        float v = 0.f;
        if (k < DIN)       v = W_ih[((size_t)n * 512 + g) * DIN + k];
        else if (k < 228)  v = W_hh[((size_t)n * 512 + g) * HID + (k - DIN)];
        bfw[id] = f2bf(v);
        return;
    }
    int id3 = id - SZ_BF;
    if (id3 < SZ_W1T) {
        int j = id3 & 127;      // output unit
        int k = id3 >> 7;       // feature
        w1t[id3] = W1[(size_t)j * FEAT + k];
    }
}

// One workgroup = (node, 16 batch rows). 512 threads = 8 waves.
// Wave w owns gates i,f,g,o of hidden block [w*16, w*16+16).
// Weights live in registers (128 VGPR of B-fragments per lane).
// xh in LDS: [16 rows][256 k] bf16, XOR-swizzled (byte ^= (row&7)<<4).
__global__ __launch_bounds__(512, 2) void lstm_kernel(
        const float* __restrict__ inp,
        const float* __restrict__ b_ih, const float* __restrict__ b_hh,
        const unsigned short* __restrict__ bfw, float* __restrict__ hf) {
    __shared__ alignas(16) unsigned short xh[16 * 256];
    char* xc = reinterpret_cast<char*>(xh);

    const int tid  = threadIdx.x;
    const int lane = tid & 63;
    const int w    = tid >> 6;          // hid block 0..7
    const int l15  = lane & 15;
    const int g4   = lane >> 4;
    const int n    = blockIdx.x >> 2;
    const int bq   = blockIdx.x & 3;    // batch quarter
    const int j    = w * 16 + l15;      // hidden index

    // ---- load B fragments (once) ----
    s8v bf[4][8];
    const unsigned short* wp = bfw + ((size_t)(n * 8 + w) * 32) * 512 + lane * 8;
    #pragma unroll
    for (int nt = 0; nt < 4; ++nt)
        #pragma unroll
        for (int kt = 0; kt < 8; ++kt)
            bf[nt][kt] = *reinterpret_cast<const s8v*>(wp + (nt * 8 + kt) * 512);

    // ---- bias (combined), one per gate ----
    float bs[4];
    #pragma unroll
    for (int nt = 0; nt < 4; ++nt)
        bs[nt] = b_ih[n * 512 + nt * 128 + j] + b_hh[n * 512 + nt * 128 + j];

    float c[4] = {0.f, 0.f, 0.f, 0.f};
    float h[4] = {0.f, 0.f, 0.f, 0.f};

    // ---- zero LDS (h + pad regions must start 0) ----
    for (int i = tid; i < 16 * 256; i += 512) xh[i] = 0;

    // ---- x staging setup: 400 float4 per step (16 rows x 25) ----
    const bool st = tid < 400;
    const int row = st ? tid / 25 : 0;
    const int c4  = st ? tid - row * 25 : 0;
    const float* xb = inp + ((size_t)(bq * 16 + row) * NN + n) * (TT * DIN) + c4 * 4;
    char* wad = xc + row * 512 + ((c4 * 8) ^ ((row & 7) << 4));

    __syncthreads();   // zero-init done before x(0) write

    // stage x(0)
    if (st) {
        float4 v = *reinterpret_cast<const float4*>(xb);
        unsigned lo = f2bf(v.x) | ((unsigned)f2bf(v.y) << 16);
        unsigned hi = f2bf(v.z) | ((unsigned)f2bf(v.w) << 16);
        *reinterpret_cast<uint2*>(wad) = make_uint2(lo, hi);
    }
    __syncthreads();

    for (int t = 0; t < TT; ++t) {
        // phase 1: prefetch x(t+1) into regs (latency hides under MFMA)
        float4 nxt = make_float4(0.f, 0.f, 0.f, 0.f);
        if (t < TT - 1 && st)
            nxt = *reinterpret_cast<const float4*>(xb + (t + 1) * DIN);

        // phase 2: gates = [x|h] @ Wfused + bias via MFMA
        f4v acc[4];
        #pragma unroll
        for (int nt = 0; nt < 4; ++nt)
            acc[nt] = (f4v){bs[nt], bs[nt], bs[nt], bs[nt]};

        #pragma unroll
        for (int kt = 0; kt < 8; ++kt) {
            int kb = kt * 64 + g4 * 16;
            s8v a = *reinterpret_cast<const s8v*>(
                        xc + l15 * 512 + (kb ^ ((l15 & 7) << 4)));
            #pragma unroll
            for (int nt = 0; nt < 4; ++nt)
                acc[nt] = __builtin_amdgcn_mfma_f32_16x16x32_bf16(
                              a, bf[nt][kt], acc[nt], 0, 0, 0);
        }

        // phase 3: nonlinearity + state update (rows = g4*4 + r, col = j)
        unsigned short hb16[4];
        #pragma unroll
        for (int r = 0; r < 4; ++r) {
            float ii = sigf(acc[0][r]);
            float ff = sigf(acc[1][r]);
            float gg = tnhf(acc[2][r]);
            float oo = sigf(acc[3][r]);
            float cn = ff * c[r] + ii * gg;
            c[r] = cn;
            float hn = oo * tnhf(cn);
            h[r] = hn;
            hb16[r] = f2bf(hn);
        }

        __syncthreads();   // all A-reads of step t complete

        // phase 5: write h(t+1) and x(t+1) for next step
        #pragma unroll
        for (int r = 0; r < 4; ++r) {
            int rr = g4 * 4 + r;
            int kb2 = (DIN + j) * 2;
            *reinterpret_cast<unsigned short*>(
                xc + rr * 512 + (kb2 ^ ((rr & 7) << 4))) = hb16[r];
        }
        if (t < TT - 1 && st) {
            unsigned lo = f2bf(nxt.x) | ((unsigned)f2bf(nxt.y) << 16);
            unsigned hi = f2bf(nxt.z) | ((unsigned)f2bf(nxt.w) << 16);
            *reinterpret_cast<uint2*>(wad) = make_uint2(lo, hi);
        }
        __syncthreads();
    }

    // final h (fp32, from registers) -> hf[b][n][128]
    #pragma unroll
    for (int r = 0; r < 4; ++r) {
        int b = bq * 16 + g4 * 4 + r;
        hf[((size_t)b * NN + n) * HID + j] = h[r];
    }
}

// Head: one block per batch row; 128 threads, one per hidden unit.
__global__ __launch_bounds__(128) void head_kernel(
        const float* __restrict__ ws,
        const float* __restrict__ b1, const float* __restrict__ W2,
        const float* __restrict__ b2, float* __restrict__ out) {
    __shared__ float comb[FEAT];
    __shared__ float hid[HID];
    const int b = blockIdx.x, t = threadIdx.x;
    const float* hfp = ws + OFF_HF + (size_t)b * FEAT;
    for (int i = t; i < FEAT; i += 128) comb[i] = hfp[i];
    __syncthreads();

    const float* w1t = ws + OFF_W1T;
    float acc = 0.f;
    #pragma unroll 4
    for (int k = 0; k < FEAT; ++k)
        acc = fmaf(comb[k], w1t[(size_t)k * HID + t], acc);
    acc += b1[t];
    hid[t] = fmaxf(acc, 0.f);
    __syncthreads();

    if (t < NC) {
        float a = b2[t];
        for (int k = 0; k < HID; ++k)
            a = fmaf(hid[k], W2[t * HID + k], a);
        out[b * NC + t] = a;
    }
}

extern "C" void kernel_launch(void* const* d_in, const int* in_sizes, int n_in,
                              void* d_out, int out_size, void* d_ws, size_t ws_size,
                              hipStream_t stream) {
    const float* inp  = (const float*)d_in[0];
    // d_in[1] = seq_lengths (int64) — reference ignores it
    const float* W_ih = (const float*)d_in[2];
    const float* W_hh = (const float*)d_in[3];
    const float* b_ih = (const float*)d_in[4];
    const float* b_hh = (const float*)d_in[5];
    const float* W1   = (const float*)d_in[6];
    const float* b1   = (const float*)d_in[7];
    const float* W2   = (const float*)d_in[8];
    const float* b2   = (const float*)d_in[9];
    float* out = (float*)d_out;
    float* ws  = (float*)d_ws;
    unsigned short* bfw = (unsigned short*)d_ws;

    pack_kernel<<<PACK_TOTAL / 256, 256, 0, stream>>>(W_ih, W_hh, W1, bfw, ws + OFF_W1T);
    lstm_kernel<<<NN * 4, 512, 0, stream>>>(inp, b_ih, b_hh, bfw, ws + OFF_HF);
    head_kernel<<<BB, 128, 0, stream>>>(ws, b1, W2, b2, out);
}

// Round 3
// 692.462 us; speedup vs baseline: 12.5662x; 1.0331x over previous
//
#include <hip/hip_runtime.h>
#include <hip/hip_bf16.h>

#define NN   19
#define DIN  100
#define HID  128
#define TT   250
#define BB   64
#define NC   4
#define FEAT 2432          // NN*HID

typedef __attribute__((ext_vector_type(8))) short s8v;
typedef __attribute__((ext_vector_type(4))) float f4v;

// ---- workspace layout ----
// [0]                : bf16 weight fragments, SZ_BF ushorts
// float offsets thereafter:
#define SZ_BF   (NN*8*4*8*512)        // 2,490,368 ushorts (n, hb, nt, kt, lane, e)
#define OFF_W1T (SZ_BF/2)             // 1,245,184 (float offset)
#define SZ_W1T  (FEAT*HID)            // 311,296
#define OFF_HF  (OFF_W1T + SZ_W1T)    // 1,556,480
#define SZ_HF   (BB*FEAT)             // 155,648
#define PACK_TOTAL (SZ_BF + SZ_W1T)   // 2,801,664 = 10944*256

__device__ __forceinline__ unsigned short f2bf(float x) {
    union { float f; unsigned u; } v; v.f = x;
    unsigned r = v.u + 0x7FFF + ((v.u >> 16) & 1);   // RNE
    return (unsigned short)(r >> 16);
}
__device__ __forceinline__ float sigf(float x) {
    return 1.f / (1.f + exp2f(-1.4426950408889634f * x));
}
__device__ __forceinline__ float tnhf(float x) {
    return 1.f - 2.f / (exp2f(2.8853900817779268f * x) + 1.f);
}

// Pack weights into per-wave MFMA B-fragments (bf16) + W1 transposed (fp32).
// B-frag element (n, hb, nt, kt, lane, e) = Wfused[k][g], k = kt*32+(lane>>4)*8+e,
// g = nt*128 + hb*16 + (lane&15);  k<100 -> W_ih, 100<=k<228 -> W_hh, else 0.
__global__ __launch_bounds__(256) void pack_kernel(
        const float* __restrict__ W_ih, const float* __restrict__ W_hh,
        const float* __restrict__ W1,
        unsigned short* __restrict__ bfw, float* __restrict__ w1t) {
    int id = blockIdx.x * 256 + threadIdx.x;
    if (id < SZ_BF) {
        int e    = id & 7;
        int lane = (id >> 3) & 63;
        int kt   = (id >> 9) & 7;
        int nt   = (id >> 12) & 3;
        int hb   = (id >> 14) & 7;
        int n    = id >> 17;
        int k = kt * 32 + (lane >> 4) * 8 + e;
        int g = nt * 128 + hb * 16 + (lane & 15);
        float v = 0.f;
        if (k < DIN)       v = W_ih[((size_t)n * 512 + g) * DIN + k];
        else if (k < 228)  v = W_hh[((size_t)n * 512 + g) * HID + (k - DIN)];
        bfw[id] = f2bf(v);
        return;
    }
    int id3 = id - SZ_BF;
    if (id3 < SZ_W1T) {
        int j = id3 & 127;      // output unit
        int k = id3 >> 7;       // feature
        w1t[id3] = W1[(size_t)j * FEAT + k];
    }
}

// One workgroup = (node, 16 batch rows). 512 threads = 8 waves.
// Wave w owns gates i,f,g,o of hidden block [w*16, w*16+16).
// Weights live in registers (128 VGPR of B-fragments per lane).
// xh DOUBLE-BUFFERED in LDS: 2 x [16 rows][256 k] bf16, XOR-swizzled
// (byte ^= (row&7)<<4). Step t reads buf[t&1], writes h(t+1)/x(t+1) into
// buf[(t+1)&1] -> ONE barrier per step, no WAR hazard.
__global__ __launch_bounds__(512, 2) void lstm_kernel(
        const float* __restrict__ inp,
        const float* __restrict__ b_ih, const float* __restrict__ b_hh,
        const unsigned short* __restrict__ bfw, float* __restrict__ hf) {
    __shared__ alignas(16) unsigned short xh[2][16 * 256];

    const int tid  = threadIdx.x;
    const int lane = tid & 63;
    const int w    = tid >> 6;          // hid block 0..7
    const int l15  = lane & 15;
    const int g4   = lane >> 4;
    const int n    = blockIdx.x >> 2;
    const int bq   = blockIdx.x & 3;    // batch quarter
    const int j    = w * 16 + l15;      // hidden index

    // ---- load B fragments (once) ----
    s8v bf[4][8];
    const unsigned short* wp = bfw + ((size_t)(n * 8 + w) * 32) * 512 + lane * 8;
    #pragma unroll
    for (int nt = 0; nt < 4; ++nt)
        #pragma unroll
        for (int kt = 0; kt < 8; ++kt)
            bf[nt][kt] = *reinterpret_cast<const s8v*>(wp + (nt * 8 + kt) * 512);

    // ---- bias (combined), one per gate ----
    float bs[4];
    #pragma unroll
    for (int nt = 0; nt < 4; ++nt)
        bs[nt] = b_ih[n * 512 + nt * 128 + j] + b_hh[n * 512 + nt * 128 + j];

    float c[4] = {0.f, 0.f, 0.f, 0.f};
    float h[4] = {0.f, 0.f, 0.f, 0.f};

    // ---- zero both LDS buffers (h + pad regions must start 0) ----
    for (int i = tid; i < 2 * 16 * 256; i += 512) (&xh[0][0])[i] = 0;

    // ---- x staging setup: 400 float4 per step (16 rows x 25) ----
    const bool st = tid < 400;
    const int row = st ? tid / 25 : 0;
    const int c4  = st ? tid - row * 25 : 0;
    const float* xb = inp + ((size_t)(bq * 16 + row) * NN + n) * (TT * DIN) + c4 * 4;
    const int wofs = row * 512 + ((c4 * 8) ^ ((row & 7) << 4));

    // per-lane A-read byte offsets (row l15, XOR-swizzled)
    const int arow = l15 * 512;
    const int aswz = (l15 & 7) << 4;

    __syncthreads();   // zero-init done before x(0) write

    // stage x(0) into buffer 0
    if (st) {
        float4 v = *reinterpret_cast<const float4*>(xb);
        unsigned lo = f2bf(v.x) | ((unsigned)f2bf(v.y) << 16);
        unsigned hi = f2bf(v.z) | ((unsigned)f2bf(v.w) << 16);
        *reinterpret_cast<uint2*>(reinterpret_cast<char*>(xh[0]) + wofs) =
            make_uint2(lo, hi);
    }
    __syncthreads();

    for (int t = 0; t < TT; ++t) {
        char* rc = reinterpret_cast<char*>(xh[t & 1]);
        char* wc = reinterpret_cast<char*>(xh[(t + 1) & 1]);

        // phase 1: prefetch x(t+1) into regs (hides under MFMA+phase3)
        float4 nxt = make_float4(0.f, 0.f, 0.f, 0.f);
        if (t < TT - 1 && st)
            nxt = *reinterpret_cast<const float4*>(xb + (t + 1) * DIN);

        // phase 2: gates = [x|h] @ Wfused + bias via MFMA
        f4v acc[4];
        #pragma unroll
        for (int nt = 0; nt < 4; ++nt)
            acc[nt] = (f4v){bs[nt], bs[nt], bs[nt], bs[nt]};

        #pragma unroll
        for (int kt = 0; kt < 8; ++kt) {
            int kb = kt * 64 + g4 * 16;
            s8v a = *reinterpret_cast<const s8v*>(rc + arow + (kb ^ aswz));
            #pragma unroll
            for (int nt = 0; nt < 4; ++nt)
                acc[nt] = __builtin_amdgcn_mfma_f32_16x16x32_bf16(
                              a, bf[nt][kt], acc[nt], 0, 0, 0);
        }

        // phase 3: nonlinearity + state update (rows = g4*4 + r, col = j)
        #pragma unroll
        for (int r = 0; r < 4; ++r) {
            float ii = sigf(acc[0][r]);
            float ff = sigf(acc[1][r]);
            float gg = tnhf(acc[2][r]);
            float oo = sigf(acc[3][r]);
            float cn = ff * c[r] + ii * gg;
            c[r] = cn;
            float hn = oo * tnhf(cn);
            h[r] = hn;
            // write h(t+1) into NEXT buffer (no barrier needed: disjoint buf)
            int rr = g4 * 4 + r;
            int kb2 = (DIN + j) * 2;
            *reinterpret_cast<unsigned short*>(
                wc + rr * 512 + (kb2 ^ ((rr & 7) << 4))) = f2bf(hn);
        }

        // phase 4: write x(t+1) into NEXT buffer
        if (t < TT - 1 && st) {
            unsigned lo = f2bf(nxt.x) | ((unsigned)f2bf(nxt.y) << 16);
            unsigned hi = f2bf(nxt.z) | ((unsigned)f2bf(nxt.w) << 16);
            *reinterpret_cast<uint2*>(wc + wofs) = make_uint2(lo, hi);
        }

        __syncthreads();   // single barrier: next buffer complete
    }

    // final h (fp32, from registers) -> hf[b][n][128]
    #pragma unroll
    for (int r = 0; r < 4; ++r) {
        int b = bq * 16 + g4 * 4 + r;
        hf[((size_t)b * NN + n) * HID + j] = h[r];
    }
}

// Head: 16 blocks x 4 batch rows; 256 threads (u = tid&127 hidden unit,
// half = tid>>7 -> rows 2*half, 2*half+1). W1T read coalesced per column.
#define HBR 4
__global__ __launch_bounds__(256) void head_kernel(
        const float* __restrict__ ws,
        const float* __restrict__ b1, const float* __restrict__ W2,
        const float* __restrict__ b2, float* __restrict__ out) {
    __shared__ float comb[HBR][FEAT];   // 38.9 KB
    __shared__ float hid[HBR][HID];
    const int bb = blockIdx.x * HBR;
    const int u    = threadIdx.x & 127;
    const int half = threadIdx.x >> 7;
    const float* hfp = ws + OFF_HF + (size_t)bb * FEAT;
    for (int i = threadIdx.x; i < HBR * FEAT; i += 256) {
        int r = i / FEAT, k = i - r * FEAT;
        comb[r][k] = hfp[(size_t)r * FEAT + k];
    }
    __syncthreads();

    const float* w1t = ws + OFF_W1T;
    const int r0 = half * 2, r1 = half * 2 + 1;
    float a0 = 0.f, a1 = 0.f;
    #pragma unroll 4
    for (int k = 0; k < FEAT; ++k) {
        float wv = w1t[(size_t)k * HID + u];
        a0 = fmaf(comb[r0][k], wv, a0);
        a1 = fmaf(comb[r1][k], wv, a1);
    }
    hid[r0][u] = fmaxf(a0 + b1[u], 0.f);
    hid[r1][u] = fmaxf(a1 + b1[u], 0.f);
    __syncthreads();

    if (threadIdx.x < HBR * NC) {
        int row = threadIdx.x >> 2, cls = threadIdx.x & 3;
        float a = b2[cls];
        #pragma unroll 4
        for (int k = 0; k < HID; ++k)
            a = fmaf(hid[row][k], W2[cls * HID + k], a);
        out[(bb + row) * NC + cls] = a;
    }
}

extern "C" void kernel_launch(void* const* d_in, const int* in_sizes, int n_in,
                              void* d_out, int out_size, void* d_ws, size_t ws_size,
                              hipStream_t stream) {
    const float* inp  = (const float*)d_in[0];
    // d_in[1] = seq_lengths (int64) — reference ignores it
    const float* W_ih = (const float*)d_in[2];
    const float* W_hh = (const float*)d_in[3];
    const float* b_ih = (const float*)d_in[4];
    const float* b_hh = (const float*)d_in[5];
    const float* W1   = (const float*)d_in[6];
    const float* b1   = (const float*)d_in[7];
    const float* W2   = (const float*)d_in[8];
    const float* b2   = (const float*)d_in[9];
    float* out = (float*)d_out;
    float* ws  = (float*)d_ws;
    unsigned short* bfw = (unsigned short*)d_ws;

    pack_kernel<<<PACK_TOTAL / 256, 256, 0, stream>>>(W_ih, W_hh, W1, bfw, ws + OFF_W1T);
    lstm_kernel<<<NN * 4, 512, 0, stream>>>(inp, b_ih, b_hh, bfw, ws + OFF_HF);
    head_kernel<<<BB / HBR, 256, 0, stream>>>(ws, b1, W2, b2, out);
}

// Round 4
// 478.277 us; speedup vs baseline: 18.1936x; 1.4478x over previous
//
#include <hip/hip_runtime.h>
#include <hip/hip_bf16.h>

#define NN   19
#define DIN  100
#define HID  128
#define TT   250
#define BB   64
#define NC   4
#define FEAT 2432          // NN*HID

typedef __attribute__((ext_vector_type(8))) short s8v;
typedef __attribute__((ext_vector_type(4))) float f4v;
typedef _Float16 h8v __attribute__((ext_vector_type(8)));

// =============== V2 workspace layout (byte offsets) ===============
// BFI: W_ih MFMA B-frags bf16   (19*8*4*4*512 ushorts = 1,245,184)
// BFH: W_hh MFMA B-frags bf16   (same count)
// BIAS: combined b_ih+b_hh f32  (19*512)
// W1T: W1 transposed f32        (2432*128)
// HF : final hidden f32         (64*2432)
// XG : precomputed x-gates f16  (19*4*250*8*64*16 = 155,648,000)
#define BFI_USH   1245184
#define V2_OFF_BFI  0ull
#define V2_OFF_BFH  2490368ull
#define V2_OFF_BIAS 4980736ull
#define V2_OFF_W1T  5019648ull
#define V2_OFF_HF   6264832ull
#define V2_OFF_XG   6887424ull
#define V2_NEED     318183424ull
#define PACK2_TOTAL (2*BFI_USH + 19*512 + FEAT*HID)   // 2,811,392

// =============== fallback (round-3) layout, float offsets =========
#define SZ_BF   (NN*8*4*8*512)
#define OFF_W1T_O (SZ_BF/2)
#define SZ_W1T  (FEAT*HID)
#define OFF_HF_O  (OFF_W1T_O + SZ_W1T)
#define PACK_TOTAL_O (SZ_BF + SZ_W1T)

__device__ __forceinline__ unsigned short f2bf(float x) {
    union { float f; unsigned u; } v; v.f = x;
    unsigned r = v.u + 0x7FFF + ((v.u >> 16) & 1);   // RNE
    return (unsigned short)(r >> 16);
}
#define LOG2E 1.4426950408889634f
__device__ __forceinline__ float sigf(float x) {
    return __builtin_amdgcn_rcpf(1.f + exp2f(-LOG2E * x));
}
__device__ __forceinline__ float tnhf(float x) {
    return 1.f - 2.f * __builtin_amdgcn_rcpf(exp2f(2.f * LOG2E * x) + 1.f);
}

// ======================= V2 kernels ===============================

// Pack W_ih frags, W_hh frags, combined bias, W1T.
// Frag element (n, hb, nt, kt, lane, e) = W[k][g]:
// k = kt*32+(lane>>4)*8+e (K=128 window), g = nt*128+hb*16+(lane&15).
__global__ __launch_bounds__(256) void pack2_kernel(
        const float* __restrict__ W_ih, const float* __restrict__ W_hh,
        const float* __restrict__ b_ih, const float* __restrict__ b_hh,
        const float* __restrict__ W1, char* __restrict__ wsb) {
    int id = blockIdx.x * 256 + threadIdx.x;
    if (id < 2 * BFI_USH) {
        int which = id >= BFI_USH;                 // 0 = W_ih, 1 = W_hh
        int i = which ? id - BFI_USH : id;
        int e    = i & 7;
        int lane = (i >> 3) & 63;
        int kt   = (i >> 9) & 3;
        int nt   = (i >> 11) & 3;
        int hb   = (i >> 13) & 7;
        int n    = i >> 16;
        int k = kt * 32 + (lane >> 4) * 8 + e;
        int g = nt * 128 + hb * 16 + (lane & 15);
        float v;
        if (which) v = W_hh[((size_t)n * 512 + g) * HID + k];
        else       v = (k < DIN) ? W_ih[((size_t)n * 512 + g) * DIN + k] : 0.f;
        reinterpret_cast<unsigned short*>(wsb)[id] = f2bf(v);
        return;
    }
    int id2 = id - 2 * BFI_USH;
    if (id2 < NN * 512) {
        reinterpret_cast<float*>(wsb + V2_OFF_BIAS)[id2] = b_ih[id2] + b_hh[id2];
        return;
    }
    int id3 = id2 - NN * 512;
    if (id3 < FEAT * HID) {
        int j = id3 & 127, k = id3 >> 7;
        reinterpret_cast<float*>(wsb + V2_OFF_W1T)[id3] = W1[(size_t)j * FEAT + k];
    }
}

// xg GEMM: grid = (n, bq, tchunk of 25). 512 thr = 8 waves.
// Computes xg[b, n, t, :] = x@W_ih^T + bias, stored as MFMA C-fragments f16:
// xg[((n*4+bq)*250+t)*8192 + (w*64+lane)*16 + nt*4 + r].
__global__ __launch_bounds__(512, 2) void xg_kernel(
        const float* __restrict__ inp, const char* __restrict__ wsb,
        _Float16* __restrict__ xg) {
    __shared__ alignas(16) unsigned short xa[2][16 * 128];

    const int tid  = threadIdx.x;
    const int lane = tid & 63;
    const int w    = tid >> 6;
    const int l15  = lane & 15;
    const int g4   = lane >> 4;
    const int blk  = blockIdx.x;
    const int tc   = blk % 10;
    const int bq   = (blk / 10) & 3;
    const int n    = blk / 40;
    const int t0   = tc * 25;
    const int j    = w * 16 + l15;

    // B-frags (W_ih), register-resident: 16 s8v = 64 VGPR
    s8v bf[4][4];
    {
        const unsigned short* wp = reinterpret_cast<const unsigned short*>(wsb)
                                   + ((size_t)(n * 8 + w) * 16) * 512 + lane * 8;
        #pragma unroll
        for (int nt = 0; nt < 4; ++nt)
            #pragma unroll
            for (int kt = 0; kt < 4; ++kt)
                bf[nt][kt] = *reinterpret_cast<const s8v*>(wp + (nt * 4 + kt) * 512);
    }
    float bs[4];
    #pragma unroll
    for (int nt = 0; nt < 4; ++nt)
        bs[nt] = reinterpret_cast<const float*>(wsb + V2_OFF_BIAS)[n * 512 + nt * 128 + j];

    // zero both buffers (k in [100,128) stays 0)
    for (int i = tid; i < 2 * 16 * 128; i += 512) (&xa[0][0])[i] = 0;

    const bool st = tid < 400;
    const int row = st ? tid / 25 : 0;
    const int c4  = st ? tid - row * 25 : 0;
    const float* xb = inp + ((size_t)(bq * 16 + row) * NN + n) * (TT * DIN)
                      + (size_t)t0 * DIN + c4 * 4;
    const int wofs = row * 256 + ((c4 * 8) ^ ((row & 7) << 4));
    const int arow = l15 * 256;
    const int aswz = (l15 & 7) << 4;

    __syncthreads();
    if (st) {
        float4 v = *reinterpret_cast<const float4*>(xb);
        unsigned lo = f2bf(v.x) | ((unsigned)f2bf(v.y) << 16);
        unsigned hi = f2bf(v.z) | ((unsigned)f2bf(v.w) << 16);
        *reinterpret_cast<uint2*>(reinterpret_cast<char*>(xa[0]) + wofs) =
            make_uint2(lo, hi);
    }
    __syncthreads();

    _Float16* xout = xg + ((size_t)((n * 4 + bq) * 250 + t0)) * 8192
                     + (w * 64 + lane) * 16;

    for (int t = 0; t < 25; ++t) {
        char* rc = reinterpret_cast<char*>(xa[t & 1]);
        char* wc = reinterpret_cast<char*>(xa[(t + 1) & 1]);

        float4 nxt = make_float4(0.f, 0.f, 0.f, 0.f);
        if (t < 24 && st)
            nxt = *reinterpret_cast<const float4*>(xb + (t + 1) * DIN);

        f4v acc[4];
        #pragma unroll
        for (int nt = 0; nt < 4; ++nt)
            acc[nt] = (f4v){bs[nt], bs[nt], bs[nt], bs[nt]};
        #pragma unroll
        for (int kt = 0; kt < 4; ++kt) {
            s8v a = *reinterpret_cast<const s8v*>(
                        rc + arow + ((kt * 64 + g4 * 16) ^ aswz));
            #pragma unroll
            for (int nt = 0; nt < 4; ++nt)
                acc[nt] = __builtin_amdgcn_mfma_f32_16x16x32_bf16(
                              a, bf[nt][kt], acc[nt], 0, 0, 0);
        }

        // pack 16 f32 -> f16 and store 32B
        h8v s0, s1;
        #pragma unroll
        for (int nt = 0; nt < 2; ++nt)
            #pragma unroll
            for (int r = 0; r < 4; ++r) s0[nt * 4 + r] = (_Float16)acc[nt][r];
        #pragma unroll
        for (int nt = 2; nt < 4; ++nt)
            #pragma unroll
            for (int r = 0; r < 4; ++r) s1[(nt - 2) * 4 + r] = (_Float16)acc[nt][r];
        *reinterpret_cast<h8v*>(xout + (size_t)t * 8192)     = s0;
        *reinterpret_cast<h8v*>(xout + (size_t)t * 8192 + 8) = s1;

        if (t < 24 && st) {
            unsigned lo = f2bf(nxt.x) | ((unsigned)f2bf(nxt.y) << 16);
            unsigned hi = f2bf(nxt.z) | ((unsigned)f2bf(nxt.w) << 16);
            *reinterpret_cast<uint2*>(wc + wofs) = make_uint2(lo, hi);
        }
        __syncthreads();
    }
}

// Recurrence: grid 76 = (n, bq). 512 thr = 8 waves. W_hh frags in regs (64 VGPR).
// Per step: acc = xg[t] (prefetched) ; acc += h @ W_hh ; nonlin ; h -> LDS.
__global__ __launch_bounds__(512, 2) void lstm2_kernel(
        const char* __restrict__ wsb, const _Float16* __restrict__ xg,
        float* __restrict__ hf) {
    __shared__ alignas(16) unsigned short xh[2][16 * 128];

    const int tid  = threadIdx.x;
    const int lane = tid & 63;
    const int w    = tid >> 6;
    const int l15  = lane & 15;
    const int g4   = lane >> 4;
    const int n    = blockIdx.x >> 2;
    const int bq   = blockIdx.x & 3;
    const int j    = w * 16 + l15;

    s8v bf[4][4];
    {
        const unsigned short* wp = reinterpret_cast<const unsigned short*>(wsb + V2_OFF_BFH)
                                   + ((size_t)(n * 8 + w) * 16) * 512 + lane * 8;
        #pragma unroll
        for (int nt = 0; nt < 4; ++nt)
            #pragma unroll
            for (int kt = 0; kt < 4; ++kt)
                bf[nt][kt] = *reinterpret_cast<const s8v*>(wp + (nt * 4 + kt) * 512);
    }

    float c[4] = {0.f, 0.f, 0.f, 0.f};
    float h[4] = {0.f, 0.f, 0.f, 0.f};

    for (int i = tid; i < 2 * 16 * 128; i += 512) (&xh[0][0])[i] = 0;

    const _Float16* xp = xg + ((size_t)((n * 4 + bq) * 250)) * 8192
                         + (w * 64 + lane) * 16;
    const int arow = l15 * 256;
    const int aswz = (l15 & 7) << 4;

    // preload xg[0]
    h8v p0 = *reinterpret_cast<const h8v*>(xp);
    h8v p1 = *reinterpret_cast<const h8v*>(xp + 8);
    __syncthreads();

    for (int t = 0; t < TT; ++t) {
        char* rc = reinterpret_cast<char*>(xh[t & 1]);
        char* wc = reinterpret_cast<char*>(xh[(t + 1) & 1]);

        // prefetch xg[t+1]
        h8v np0, np1;
        if (t < TT - 1) {
            np0 = *reinterpret_cast<const h8v*>(xp + (size_t)(t + 1) * 8192);
            np1 = *reinterpret_cast<const h8v*>(xp + (size_t)(t + 1) * 8192 + 8);
        }

        f4v acc[4];
        #pragma unroll
        for (int nt = 0; nt < 2; ++nt)
            #pragma unroll
            for (int r = 0; r < 4; ++r) acc[nt][r] = (float)p0[nt * 4 + r];
        #pragma unroll
        for (int nt = 2; nt < 4; ++nt)
            #pragma unroll
            for (int r = 0; r < 4; ++r) acc[nt][r] = (float)p1[(nt - 2) * 4 + r];

        #pragma unroll
        for (int kt = 0; kt < 4; ++kt) {
            s8v a = *reinterpret_cast<const s8v*>(
                        rc + arow + ((kt * 64 + g4 * 16) ^ aswz));
            #pragma unroll
            for (int nt = 0; nt < 4; ++nt)
                acc[nt] = __builtin_amdgcn_mfma_f32_16x16x32_bf16(
                              a, bf[nt][kt], acc[nt], 0, 0, 0);
        }

        #pragma unroll
        for (int r = 0; r < 4; ++r) {
            float ii = sigf(acc[0][r]);
            float ff = sigf(acc[1][r]);
            float gg = tnhf(acc[2][r]);
            float oo = sigf(acc[3][r]);
            float cn = ff * c[r] + ii * gg;
            c[r] = cn;
            float hn = oo * tnhf(cn);
            h[r] = hn;
            int rr = g4 * 4 + r;
            *reinterpret_cast<unsigned short*>(
                wc + rr * 256 + ((2 * j) ^ ((rr & 7) << 4))) = f2bf(hn);
        }
        p0 = np0; p1 = np1;
        __syncthreads();
    }

    #pragma unroll
    for (int r = 0; r < 4; ++r) {
        int b = bq * 16 + g4 * 4 + r;
        hf[((size_t)b * NN + n) * HID + j] = h[r];
    }
}

// Head: 64 blocks (one per batch row), 256 thr: u = tid&127, kk = tid>>7
// splits K. comb staged in LDS; W1T read coalesced.
__global__ __launch_bounds__(256) void head2_kernel(
        const float* __restrict__ hf, const float* __restrict__ w1t,
        const float* __restrict__ b1, const float* __restrict__ W2,
        const float* __restrict__ b2, float* __restrict__ out) {
    __shared__ float comb[FEAT];
    __shared__ float par[2][HID];
    __shared__ float hid[HID];
    const int b = blockIdx.x;
    const int u  = threadIdx.x & 127;
    const int kk = threadIdx.x >> 7;
    const float* hfp = hf + (size_t)b * FEAT;
    for (int i = threadIdx.x; i < FEAT; i += 256) comb[i] = hfp[i];
    __syncthreads();

    const int k0 = kk * (FEAT / 2);
    float acc = 0.f;
    #pragma unroll 8
    for (int k = 0; k < FEAT / 2; ++k)
        acc = fmaf(comb[k0 + k], w1t[(size_t)(k0 + k) * HID + u], acc);
    par[kk][u] = acc;
    __syncthreads();
    if (kk == 0) hid[u] = fmaxf(par[0][u] + par[1][u] + b1[u], 0.f);
    __syncthreads();

    if (threadIdx.x < NC) {
        int cls = threadIdx.x;
        float a = b2[cls];
        #pragma unroll 4
        for (int k = 0; k < HID; ++k)
            a = fmaf(hid[k], W2[cls * HID + k], a);
        out[b * NC + cls] = a;
    }
}

// ======================= fallback (round-3) =======================
__global__ __launch_bounds__(256) void packfb_kernel(
        const float* __restrict__ W_ih, const float* __restrict__ W_hh,
        const float* __restrict__ W1,
        unsigned short* __restrict__ bfw, float* __restrict__ w1t) {
    int id = blockIdx.x * 256 + threadIdx.x;
    if (id < SZ_BF) {
        int e    = id & 7;
        int lane = (id >> 3) & 63;
        int kt   = (id >> 9) & 7;
        int nt   = (id >> 12) & 3;
        int hb   = (id >> 14) & 7;
        int n    = id >> 17;
        int k = kt * 32 + (lane >> 4) * 8 + e;
        int g = nt * 128 + hb * 16 + (lane & 15);
        float v = 0.f;
        if (k < DIN)       v = W_ih[((size_t)n * 512 + g) * DIN + k];
        else if (k < 228)  v = W_hh[((size_t)n * 512 + g) * HID + (k - DIN)];
        bfw[id] = f2bf(v);
        return;
    }
    int id3 = id - SZ_BF;
    if (id3 < SZ_W1T) {
        int j = id3 & 127, k = id3 >> 7;
        w1t[id3] = W1[(size_t)j * FEAT + k];
    }
}

__global__ __launch_bounds__(512, 2) void lstmfb_kernel(
        const float* __restrict__ inp,
        const float* __restrict__ b_ih, const float* __restrict__ b_hh,
        const unsigned short* __restrict__ bfw, float* __restrict__ hf) {
    __shared__ alignas(16) unsigned short xh[2][16 * 256];
    const int tid  = threadIdx.x;
    const int lane = tid & 63;
    const int w    = tid >> 6;
    const int l15  = lane & 15;
    const int g4   = lane >> 4;
    const int n    = blockIdx.x >> 2;
    const int bq   = blockIdx.x & 3;
    const int j    = w * 16 + l15;

    s8v bf[4][8];
    const unsigned short* wp = bfw + ((size_t)(n * 8 + w) * 32) * 512 + lane * 8;
    #pragma unroll
    for (int nt = 0; nt < 4; ++nt)
        #pragma unroll
        for (int kt = 0; kt < 8; ++kt)
            bf[nt][kt] = *reinterpret_cast<const s8v*>(wp + (nt * 8 + kt) * 512);

    float bs[4];
    #pragma unroll
    for (int nt = 0; nt < 4; ++nt)
        bs[nt] = b_ih[n * 512 + nt * 128 + j] + b_hh[n * 512 + nt * 128 + j];

    float c[4] = {0.f, 0.f, 0.f, 0.f};
    float h[4] = {0.f, 0.f, 0.f, 0.f};
    for (int i = tid; i < 2 * 16 * 256; i += 512) (&xh[0][0])[i] = 0;

    const bool st = tid < 400;
    const int row = st ? tid / 25 : 0;
    const int c4  = st ? tid - row * 25 : 0;
    const float* xb = inp + ((size_t)(bq * 16 + row) * NN + n) * (TT * DIN) + c4 * 4;
    const int wofs = row * 512 + ((c4 * 8) ^ ((row & 7) << 4));
    const int arow = l15 * 512;
    const int aswz = (l15 & 7) << 4;

    __syncthreads();
    if (st) {
        float4 v = *reinterpret_cast<const float4*>(xb);
        unsigned lo = f2bf(v.x) | ((unsigned)f2bf(v.y) << 16);
        unsigned hi = f2bf(v.z) | ((unsigned)f2bf(v.w) << 16);
        *reinterpret_cast<uint2*>(reinterpret_cast<char*>(xh[0]) + wofs) =
            make_uint2(lo, hi);
    }
    __syncthreads();

    for (int t = 0; t < TT; ++t) {
        char* rc = reinterpret_cast<char*>(xh[t & 1]);
        char* wc = reinterpret_cast<char*>(xh[(t + 1) & 1]);
        float4 nxt = make_float4(0.f, 0.f, 0.f, 0.f);
        if (t < TT - 1 && st)
            nxt = *reinterpret_cast<const float4*>(xb + (t + 1) * DIN);

        f4v acc[4];
        #pragma unroll
        for (int nt = 0; nt < 4; ++nt)
            acc[nt] = (f4v){bs[nt], bs[nt], bs[nt], bs[nt]};
        #pragma unroll
        for (int kt = 0; kt < 8; ++kt) {
            s8v a = *reinterpret_cast<const s8v*>(rc + arow + ((kt * 64 + g4 * 16) ^ aswz));
            #pragma unroll
            for (int nt = 0; nt < 4; ++nt)
                acc[nt] = __builtin_amdgcn_mfma_f32_16x16x32_bf16(a, bf[nt][kt], acc[nt], 0, 0, 0);
        }
        #pragma unroll
        for (int r = 0; r < 4; ++r) {
            float ii = sigf(acc[0][r]);
            float ff = sigf(acc[1][r]);
            float gg = tnhf(acc[2][r]);
            float oo = sigf(acc[3][r]);
            float cn = ff * c[r] + ii * gg;
            c[r] = cn;
            float hn = oo * tnhf(cn);
            h[r] = hn;
            int rr = g4 * 4 + r;
            *reinterpret_cast<unsigned short*>(
                wc + rr * 512 + (((DIN + j) * 2) ^ ((rr & 7) << 4))) = f2bf(hn);
        }
        if (t < TT - 1 && st) {
            unsigned lo = f2bf(nxt.x) | ((unsigned)f2bf(nxt.y) << 16);
            unsigned hi = f2bf(nxt.z) | ((unsigned)f2bf(nxt.w) << 16);
            *reinterpret_cast<uint2*>(wc + wofs) = make_uint2(lo, hi);
        }
        __syncthreads();
    }
    #pragma unroll
    for (int r = 0; r < 4; ++r) {
        int b = bq * 16 + g4 * 4 + r;
        hf[((size_t)b * NN + n) * HID + j] = h[r];
    }
}

// ============================ launch ==============================
extern "C" void kernel_launch(void* const* d_in, const int* in_sizes, int n_in,
                              void* d_out, int out_size, void* d_ws, size_t ws_size,
                              hipStream_t stream) {
    const float* inp  = (const float*)d_in[0];
    const float* W_ih = (const float*)d_in[2];
    const float* W_hh = (const float*)d_in[3];
    const float* b_ih = (const float*)d_in[4];
    const float* b_hh = (const float*)d_in[5];
    const float* W1   = (const float*)d_in[6];
    const float* b1   = (const float*)d_in[7];
    const float* W2   = (const float*)d_in[8];
    const float* b2   = (const float*)d_in[9];
    float* out = (float*)d_out;

    if (ws_size >= V2_NEED) {
        char* wsb = (char*)d_ws;
        _Float16* xg = (_Float16*)(wsb + V2_OFF_XG);
        float* hf    = (float*)(wsb + V2_OFF_HF);
        float* w1t   = (float*)(wsb + V2_OFF_W1T);
        pack2_kernel<<<(PACK2_TOTAL + 255) / 256, 256, 0, stream>>>(
            W_ih, W_hh, b_ih, b_hh, W1, wsb);
        xg_kernel<<<NN * 4 * 10, 512, 0, stream>>>(inp, wsb, xg);
        lstm2_kernel<<<NN * 4, 512, 0, stream>>>(wsb, xg, hf);
        head2_kernel<<<BB, 256, 0, stream>>>(hf, w1t, b1, W2, b2, out);
    } else {
        float* ws = (float*)d_ws;
        unsigned short* bfw = (unsigned short*)d_ws;
        packfb_kernel<<<(PACK_TOTAL_O + 255) / 256, 256, 0, stream>>>(
            W_ih, W_hh, W1, bfw, ws + OFF_W1T_O);
        lstmfb_kernel<<<NN * 4, 512, 0, stream>>>(inp, b_ih, b_hh, bfw, ws + OFF_HF_O);
        head2_kernel<<<BB, 256, 0, stream>>>(ws + OFF_HF_O, ws + OFF_W1T_O,
                                             b1, W2, b2, out);
    }
}

// Round 5
// 390.503 us; speedup vs baseline: 22.2830x; 1.2248x over previous
//
#include <hip/hip_runtime.h>
#include <hip/hip_bf16.h>

#define NN   19
#define DIN  100
#define HID  128
#define TT   250
#define BB   64
#define NC   4
#define FEAT 2432          // NN*HID

typedef __attribute__((ext_vector_type(8))) short s8v;
typedef __attribute__((ext_vector_type(4))) float f4v;
typedef _Float16 h8v __attribute__((ext_vector_type(8)));

// =============== V2 workspace layout (byte offsets) ===============
#define BFI_USH   1245184
#define V2_OFF_BFI  0ull
#define V2_OFF_BFH  2490368ull
#define V2_OFF_BIAS 4980736ull
#define V2_OFF_W1T  5019648ull
#define V2_OFF_HF   6264832ull
#define V2_OFF_XG   6887424ull
#define V2_NEED     318183424ull
#define PACK2_TOTAL (2*BFI_USH + 19*512 + FEAT*HID)

// =============== fallback (round-3) layout, float offsets =========
#define SZ_BF   (NN*8*4*8*512)
#define OFF_W1T_O (SZ_BF/2)
#define SZ_W1T  (FEAT*HID)
#define OFF_HF_O  (OFF_W1T_O + SZ_W1T)
#define PACK_TOTAL_O (SZ_BF + SZ_W1T)

__device__ __forceinline__ unsigned short f2bf(float x) {
    union { float f; unsigned u; } v; v.f = x;
    unsigned r = v.u + 0x7FFF + ((v.u >> 16) & 1);   // RNE
    return (unsigned short)(r >> 16);
}
#define LOG2E 1.4426950408889634f
__device__ __forceinline__ float sigf(float x) {
    return __builtin_amdgcn_rcpf(1.f + __builtin_amdgcn_exp2f(-LOG2E * x));
}
__device__ __forceinline__ float tnhf(float x) {
    return 1.f - 2.f * __builtin_amdgcn_rcpf(__builtin_amdgcn_exp2f(2.f * LOG2E * x) + 1.f);
}

// ======================= V2 kernels ===============================

__global__ __launch_bounds__(256) void pack2_kernel(
        const float* __restrict__ W_ih, const float* __restrict__ W_hh,
        const float* __restrict__ b_ih, const float* __restrict__ b_hh,
        const float* __restrict__ W1, char* __restrict__ wsb) {
    int id = blockIdx.x * 256 + threadIdx.x;
    if (id < 2 * BFI_USH) {
        int which = id >= BFI_USH;                 // 0 = W_ih, 1 = W_hh
        int i = which ? id - BFI_USH : id;
        int e    = i & 7;
        int lane = (i >> 3) & 63;
        int kt   = (i >> 9) & 3;
        int nt   = (i >> 11) & 3;
        int hb   = (i >> 13) & 7;
        int n    = i >> 16;
        int k = kt * 32 + (lane >> 4) * 8 + e;
        int g = nt * 128 + hb * 16 + (lane & 15);
        float v;
        if (which) v = W_hh[((size_t)n * 512 + g) * HID + k];
        else       v = (k < DIN) ? W_ih[((size_t)n * 512 + g) * DIN + k] : 0.f;
        reinterpret_cast<unsigned short*>(wsb)[id] = f2bf(v);
        return;
    }
    int id2 = id - 2 * BFI_USH;
    if (id2 < NN * 512) {
        reinterpret_cast<float*>(wsb + V2_OFF_BIAS)[id2] = b_ih[id2] + b_hh[id2];
        return;
    }
    int id3 = id2 - NN * 512;
    if (id3 < FEAT * HID) {
        int j = id3 & 127, k = id3 >> 7;
        reinterpret_cast<float*>(wsb + V2_OFF_W1T)[id3] = W1[(size_t)j * FEAT + k];
    }
}

// xg GEMM: grid = (n, bq, tchunk of 25). 512 thr = 8 waves.
__global__ __launch_bounds__(512, 2) void xg_kernel(
        const float* __restrict__ inp, const char* __restrict__ wsb,
        _Float16* __restrict__ xg) {
    __shared__ alignas(16) unsigned short xa[2][16 * 128];

    const int tid  = threadIdx.x;
    const int lane = tid & 63;
    const int w    = tid >> 6;
    const int l15  = lane & 15;
    const int g4   = lane >> 4;
    const int blk  = blockIdx.x;
    const int tc   = blk % 10;
    const int bq   = (blk / 10) & 3;
    const int n    = blk / 40;
    const int t0   = tc * 25;
    const int j    = w * 16 + l15;

    s8v bf[4][4];
    {
        const unsigned short* wp = reinterpret_cast<const unsigned short*>(wsb)
                                   + ((size_t)(n * 8 + w) * 16) * 512 + lane * 8;
        #pragma unroll
        for (int nt = 0; nt < 4; ++nt)
            #pragma unroll
            for (int kt = 0; kt < 4; ++kt)
                bf[nt][kt] = *reinterpret_cast<const s8v*>(wp + (nt * 4 + kt) * 512);
    }
    float bs[4];
    #pragma unroll
    for (int nt = 0; nt < 4; ++nt)
        bs[nt] = reinterpret_cast<const float*>(wsb + V2_OFF_BIAS)[n * 512 + nt * 128 + j];

    for (int i = tid; i < 2 * 16 * 128; i += 512) (&xa[0][0])[i] = 0;

    const bool st = tid < 400;
    const int row = st ? tid / 25 : 0;
    const int c4  = st ? tid - row * 25 : 0;
    const float* xb = inp + ((size_t)(bq * 16 + row) * NN + n) * (TT * DIN)
                      + (size_t)t0 * DIN + c4 * 4;
    const int wofs = row * 256 + ((c4 * 8) ^ ((row & 7) << 4));
    const int arow = l15 * 256;
    const int aswz = (l15 & 7) << 4;

    __syncthreads();
    if (st) {
        float4 v = *reinterpret_cast<const float4*>(xb);
        unsigned lo = f2bf(v.x) | ((unsigned)f2bf(v.y) << 16);
        unsigned hi = f2bf(v.z) | ((unsigned)f2bf(v.w) << 16);
        *reinterpret_cast<uint2*>(reinterpret_cast<char*>(xa[0]) + wofs) =
            make_uint2(lo, hi);
    }
    __syncthreads();

    _Float16* xout = xg + ((size_t)((n * 4 + bq) * 250 + t0)) * 8192
                     + (w * 64 + lane) * 16;

    for (int t = 0; t < 25; ++t) {
        char* rc = reinterpret_cast<char*>(xa[t & 1]);
        char* wc = reinterpret_cast<char*>(xa[(t + 1) & 1]);

        float4 nxt = make_float4(0.f, 0.f, 0.f, 0.f);
        if (t < 24 && st)
            nxt = *reinterpret_cast<const float4*>(xb + (t + 1) * DIN);

        f4v acc[4];
        #pragma unroll
        for (int nt = 0; nt < 4; ++nt)
            acc[nt] = (f4v){bs[nt], bs[nt], bs[nt], bs[nt]};
        #pragma unroll
        for (int kt = 0; kt < 4; ++kt) {
            s8v a = *reinterpret_cast<const s8v*>(
                        rc + arow + ((kt * 64 + g4 * 16) ^ aswz));
            #pragma unroll
            for (int nt = 0; nt < 4; ++nt)
                acc[nt] = __builtin_amdgcn_mfma_f32_16x16x32_bf16(
                              a, bf[nt][kt], acc[nt], 0, 0, 0);
        }

        h8v s0, s1;
        #pragma unroll
        for (int nt = 0; nt < 2; ++nt)
            #pragma unroll
            for (int r = 0; r < 4; ++r) s0[nt * 4 + r] = (_Float16)acc[nt][r];
        #pragma unroll
        for (int nt = 2; nt < 4; ++nt)
            #pragma unroll
            for (int r = 0; r < 4; ++r) s1[(nt - 2) * 4 + r] = (_Float16)acc[nt][r];
        *reinterpret_cast<h8v*>(xout + (size_t)t * 8192)     = s0;
        *reinterpret_cast<h8v*>(xout + (size_t)t * 8192 + 8) = s1;

        if (t < 24 && st) {
            unsigned lo = f2bf(nxt.x) | ((unsigned)f2bf(nxt.y) << 16);
            unsigned hi = f2bf(nxt.z) | ((unsigned)f2bf(nxt.w) << 16);
            *reinterpret_cast<uint2*>(wc + wofs) = make_uint2(lo, hi);
        }
        __syncthreads();
    }
}

// Recurrence v3: grid 152 = (n, batch-octet bo). 512 thr = 8 waves.
// M=16 MFMA tile holds the 8 real rows DUPLICATED (rows 8-15 = rows 0-7),
// so every lane's C-fragment is valid and phase-3 splits 2 rows/thread:
// lanes g4<2 process acc slots r in {0,1}, lanes g4>=2 slots {2,3}.
__global__ __launch_bounds__(512, 2) void lstm3_kernel(
        const char* __restrict__ wsb, const _Float16* __restrict__ xg,
        float* __restrict__ hf) {
    __shared__ alignas(16) unsigned short xh[2][16 * 128];

    const int tid  = threadIdx.x;
    const int lane = tid & 63;
    const int w    = tid >> 6;
    const int l15  = lane & 15;
    const int g4   = lane >> 4;
    const int n    = blockIdx.x >> 3;
    const int bo   = blockIdx.x & 7;
    const int bq   = bo >> 1;
    const int hi   = bo & 1;
    const int j    = w * 16 + l15;

    s8v bf[4][4];
    {
        const unsigned short* wp = reinterpret_cast<const unsigned short*>(wsb + V2_OFF_BFH)
                                   + ((size_t)(n * 8 + w) * 16) * 512 + lane * 8;
        #pragma unroll
        for (int nt = 0; nt < 4; ++nt)
            #pragma unroll
            for (int kt = 0; kt < 4; ++kt)
                bf[nt][kt] = *reinterpret_cast<const s8v*>(wp + (nt * 4 + kt) * 512);
    }

    // this thread's 2 elements: acc slots rlo, rlo+1; LDS row rbase+r
    const int rlo   = (g4 >> 1) * 2;      // 0 or 2
    const int rbase = (g4 & 1) * 4;

    float c2[2] = {0.f, 0.f};
    float h2[2] = {0.f, 0.f};

    for (int i = tid; i < 2 * 16 * 128; i += 512) (&xh[0][0])[i] = 0;

    // xg source fragment: lane_f = l15 + 16*(hi*2 + (g4&1))
    const _Float16* xp = xg + ((size_t)((n * 4 + bq) * 250)) * 8192
                         + (size_t)(w * 64 + l15 + 16 * (hi * 2 + (g4 & 1))) * 16;
    const int arow = l15 * 256;
    const int aswz = (l15 & 7) << 4;

    h8v p0 = *reinterpret_cast<const h8v*>(xp);
    h8v p1 = *reinterpret_cast<const h8v*>(xp + 8);
    __syncthreads();

    for (int t = 0; t < TT; ++t) {
        char* rc = reinterpret_cast<char*>(xh[t & 1]);
        char* wc = reinterpret_cast<char*>(xh[(t + 1) & 1]);

        h8v np0, np1;
        if (t < TT - 1) {
            np0 = *reinterpret_cast<const h8v*>(xp + (size_t)(t + 1) * 8192);
            np1 = *reinterpret_cast<const h8v*>(xp + (size_t)(t + 1) * 8192 + 8);
        }

        f4v acc[4];
        #pragma unroll
        for (int nt = 0; nt < 2; ++nt)
            #pragma unroll
            for (int r = 0; r < 4; ++r) acc[nt][r] = (float)p0[nt * 4 + r];
        #pragma unroll
        for (int nt = 2; nt < 4; ++nt)
            #pragma unroll
            for (int r = 0; r < 4; ++r) acc[nt][r] = (float)p1[(nt - 2) * 4 + r];

        #pragma unroll
        for (int kt = 0; kt < 4; ++kt) {
            s8v a = *reinterpret_cast<const s8v*>(
                        rc + arow + ((kt * 64 + g4 * 16) ^ aswz));
            #pragma unroll
            for (int nt = 0; nt < 4; ++nt)
                acc[nt] = __builtin_amdgcn_mfma_f32_16x16x32_bf16(
                              a, bf[nt][kt], acc[nt], 0, 0, 0);
        }

        // phase 3: 2 elements per thread, all 64 lanes active
        #pragma unroll
        for (int q = 0; q < 2; ++q) {
            int r = rlo + q;
            float ii = sigf(acc[0][r]);
            float ff = sigf(acc[1][r]);
            float gg = tnhf(acc[2][r]);
            float oo = sigf(acc[3][r]);
            float cn = ff * c2[q] + ii * gg;
            c2[q] = cn;
            float hn = oo * tnhf(cn);
            h2[q] = hn;
            int rr = rbase + r;                    // 0..7
            unsigned short hb = f2bf(hn);
            int off = rr * 256 + ((2 * j) ^ ((rr & 7) << 4));
            *reinterpret_cast<unsigned short*>(wc + off) = hb;
            *reinterpret_cast<unsigned short*>(wc + off + 8 * 256) = hb;  // dup
        }
        p0 = np0; p1 = np1;
        __syncthreads();
    }

    #pragma unroll
    for (int q = 0; q < 2; ++q) {
        int b = bq * 16 + hi * 8 + rbase + rlo + q;
        hf[((size_t)b * NN + n) * HID + j] = h2[q];
    }
}

// Head: 64 blocks (one per batch row), 256 thr, split-K over 2 halves.
__global__ __launch_bounds__(256) void head2_kernel(
        const float* __restrict__ hf, const float* __restrict__ w1t,
        const float* __restrict__ b1, const float* __restrict__ W2,
        const float* __restrict__ b2, float* __restrict__ out) {
    __shared__ float comb[FEAT];
    __shared__ float par[2][HID];
    __shared__ float hid[HID];
    const int b = blockIdx.x;
    const int u  = threadIdx.x & 127;
    const int kk = threadIdx.x >> 7;
    const float* hfp = hf + (size_t)b * FEAT;
    for (int i = threadIdx.x; i < FEAT; i += 256) comb[i] = hfp[i];
    __syncthreads();

    const int k0 = kk * (FEAT / 2);
    float acc = 0.f;
    #pragma unroll 8
    for (int k = 0; k < FEAT / 2; ++k)
        acc = fmaf(comb[k0 + k], w1t[(size_t)(k0 + k) * HID + u], acc);
    par[kk][u] = acc;
    __syncthreads();
    if (kk == 0) hid[u] = fmaxf(par[0][u] + par[1][u] + b1[u], 0.f);
    __syncthreads();

    if (threadIdx.x < NC) {
        int cls = threadIdx.x;
        float a = b2[cls];
        #pragma unroll 4
        for (int k = 0; k < HID; ++k)
            a = fmaf(hid[k], W2[cls * HID + k], a);
        out[b * NC + cls] = a;
    }
}

// ======================= fallback (round-3) =======================
__global__ __launch_bounds__(256) void packfb_kernel(
        const float* __restrict__ W_ih, const float* __restrict__ W_hh,
        const float* __restrict__ W1,
        unsigned short* __restrict__ bfw, float* __restrict__ w1t) {
    int id = blockIdx.x * 256 + threadIdx.x;
    if (id < SZ_BF) {
        int e    = id & 7;
        int lane = (id >> 3) & 63;
        int kt   = (id >> 9) & 7;
        int nt   = (id >> 12) & 3;
        int hb   = (id >> 14) & 7;
        int n    = id >> 17;
        int k = kt * 32 + (lane >> 4) * 8 + e;
        int g = nt * 128 + hb * 16 + (lane & 15);
        float v = 0.f;
        if (k < DIN)       v = W_ih[((size_t)n * 512 + g) * DIN + k];
        else if (k < 228)  v = W_hh[((size_t)n * 512 + g) * HID + (k - DIN)];
        bfw[id] = f2bf(v);
        return;
    }
    int id3 = id - SZ_BF;
    if (id3 < SZ_W1T) {
        int j = id3 & 127, k = id3 >> 7;
        w1t[id3] = W1[(size_t)j * FEAT + k];
    }
}

__global__ __launch_bounds__(512, 2) void lstmfb_kernel(
        const float* __restrict__ inp,
        const float* __restrict__ b_ih, const float* __restrict__ b_hh,
        const unsigned short* __restrict__ bfw, float* __restrict__ hf) {
    __shared__ alignas(16) unsigned short xh[2][16 * 256];
    const int tid  = threadIdx.x;
    const int lane = tid & 63;
    const int w    = tid >> 6;
    const int l15  = lane & 15;
    const int g4   = lane >> 4;
    const int n    = blockIdx.x >> 2;
    const int bq   = blockIdx.x & 3;
    const int j    = w * 16 + l15;

    s8v bf[4][8];
    const unsigned short* wp = bfw + ((size_t)(n * 8 + w) * 32) * 512 + lane * 8;
    #pragma unroll
    for (int nt = 0; nt < 4; ++nt)
        #pragma unroll
        for (int kt = 0; kt < 8; ++kt)
            bf[nt][kt] = *reinterpret_cast<const s8v*>(wp + (nt * 8 + kt) * 512);

    float bs[4];
    #pragma unroll
    for (int nt = 0; nt < 4; ++nt)
        bs[nt] = b_ih[n * 512 + nt * 128 + j] + b_hh[n * 512 + nt * 128 + j];

    float c[4] = {0.f, 0.f, 0.f, 0.f};
    float h[4] = {0.f, 0.f, 0.f, 0.f};
    for (int i = tid; i < 2 * 16 * 256; i += 512) (&xh[0][0])[i] = 0;

    const bool st = tid < 400;
    const int row = st ? tid / 25 : 0;
    const int c4  = st ? tid - row * 25 : 0;
    const float* xb = inp + ((size_t)(bq * 16 + row) * NN + n) * (TT * DIN) + c4 * 4;
    const int wofs = row * 512 + ((c4 * 8) ^ ((row & 7) << 4));
    const int arow = l15 * 512;
    const int aswz = (l15 & 7) << 4;

    __syncthreads();
    if (st) {
        float4 v = *reinterpret_cast<const float4*>(xb);
        unsigned lo = f2bf(v.x) | ((unsigned)f2bf(v.y) << 16);
        unsigned hi = f2bf(v.z) | ((unsigned)f2bf(v.w) << 16);
        *reinterpret_cast<uint2*>(reinterpret_cast<char*>(xh[0]) + wofs) =
            make_uint2(lo, hi);
    }
    __syncthreads();

    for (int t = 0; t < TT; ++t) {
        char* rc = reinterpret_cast<char*>(xh[t & 1]);
        char* wc = reinterpret_cast<char*>(xh[(t + 1) & 1]);
        float4 nxt = make_float4(0.f, 0.f, 0.f, 0.f);
        if (t < TT - 1 && st)
            nxt = *reinterpret_cast<const float4*>(xb + (t + 1) * DIN);

        f4v acc[4];
        #pragma unroll
        for (int nt = 0; nt < 4; ++nt)
            acc[nt] = (f4v){bs[nt], bs[nt], bs[nt], bs[nt]};
        #pragma unroll
        for (int kt = 0; kt < 8; ++kt) {
            s8v a = *reinterpret_cast<const s8v*>(rc + arow + ((kt * 64 + g4 * 16) ^ aswz));
            #pragma unroll
            for (int nt = 0; nt < 4; ++nt)
                acc[nt] = __builtin_amdgcn_mfma_f32_16x16x32_bf16(a, bf[nt][kt], acc[nt], 0, 0, 0);
        }
        #pragma unroll
        for (int r = 0; r < 4; ++r) {
            float ii = sigf(acc[0][r]);
            float ff = sigf(acc[1][r]);
            float gg = tnhf(acc[2][r]);
            float oo = sigf(acc[3][r]);
            float cn = ff * c[r] + ii * gg;
            c[r] = cn;
            float hn = oo * tnhf(cn);
            h[r] = hn;
            int rr = g4 * 4 + r;
            *reinterpret_cast<unsigned short*>(
                wc + rr * 512 + (((DIN + j) * 2) ^ ((rr & 7) << 4))) = f2bf(hn);
        }
        if (t < TT - 1 && st) {
            unsigned lo = f2bf(nxt.x) | ((unsigned)f2bf(nxt.y) << 16);
            unsigned hi = f2bf(nxt.z) | ((unsigned)f2bf(nxt.w) << 16);
            *reinterpret_cast<uint2*>(wc + wofs) = make_uint2(lo, hi);
        }
        __syncthreads();
    }
    #pragma unroll
    for (int r = 0; r < 4; ++r) {
        int b = bq * 16 + g4 * 4 + r;
        hf[((size_t)b * NN + n) * HID + j] = h[r];
    }
}

// ============================ launch ==============================
extern "C" void kernel_launch(void* const* d_in, const int* in_sizes, int n_in,
                              void* d_out, int out_size, void* d_ws, size_t ws_size,
                              hipStream_t stream) {
    const float* inp  = (const float*)d_in[0];
    const float* W_ih = (const float*)d_in[2];
    const float* W_hh = (const float*)d_in[3];
    const float* b_ih = (const float*)d_in[4];
    const float* b_hh = (const float*)d_in[5];
    const float* W1   = (const float*)d_in[6];
    const float* b1   = (const float*)d_in[7];
    const float* W2   = (const float*)d_in[8];
    const float* b2   = (const float*)d_in[9];
    float* out = (float*)d_out;

    if (ws_size >= V2_NEED) {
        char* wsb = (char*)d_ws;
        _Float16* xg = (_Float16*)(wsb + V2_OFF_XG);
        float* hf    = (float*)(wsb + V2_OFF_HF);
        float* w1t   = (float*)(wsb + V2_OFF_W1T);
        pack2_kernel<<<(PACK2_TOTAL + 255) / 256, 256, 0, stream>>>(
            W_ih, W_hh, b_ih, b_hh, W1, wsb);
        xg_kernel<<<NN * 4 * 10, 512, 0, stream>>>(inp, wsb, xg);
        lstm3_kernel<<<NN * 8, 512, 0, stream>>>(wsb, xg, hf);
        head2_kernel<<<BB, 256, 0, stream>>>(hf, w1t, b1, W2, b2, out);
    } else {
        float* ws = (float*)d_ws;
        unsigned short* bfw = (unsigned short*)d_ws;
        packfb_kernel<<<(PACK_TOTAL_O + 255) / 256, 256, 0, stream>>>(
            W_ih, W_hh, W1, bfw, ws + OFF_W1T_O);
        lstmfb_kernel<<<NN * 4, 512, 0, stream>>>(inp, b_ih, b_hh, bfw, ws + OFF_HF_O);
        head2_kernel<<<BB, 256, 0, stream>>>(ws + OFF_HF_O, ws + OFF_W1T_O,
                                             b1, W2, b2, out);
    }
}